// Round 3
// baseline (620.624 us; speedup 1.0000x reference)
//
#include <hip/hip_runtime.h>

// Edge MLP: out = relu(concat(x[src], x[tgt], edge_attr) @ W1 + b1) @ W2 + b2
// E=640000, NODE=128, EA=64, IN=320, OUT=128. fp32 in/out, bf16 MFMA compute.
//
// v2 strategy (fix latency-serialization seen in rocprof: MfmaUtil 11%, HBM 26%,
// occupancy 21%, 14.7M LDS bank conflicts):
//  - BM=64 edges/block, 256 thr (4 waves), LDS 56 KB -> 2 blocks/CU. Two
//    independent barrier domains per CU: one block stages (memory) while the
//    other runs MFMA. Previous version: 147 KB LDS -> 1 block/CU, fully serial.
//  - W1/W2 held in per-wave VGPRs (wave w owns output cols [32w,32w+32)):
//    80 + 32 VGPR, loaded from the prepped fragment-linear layout (L2-hot).
//  - Staging: each thread writes whole 16-B granules (8 consecutive k of one
//    row = 2 float4 loads + 1 ds_write_b128), granule index linear in lane ->
//    conflict-free LDS writes AND conflict-free a-frag reads; src/tgt/attr
//    branch is wave-uniform. Attr via nontemporal loads (native vec type —
//    HIP float4 is a class and rejected by __builtin_nontemporal_load).
//  - h round-trip through a separate 16 KB LDS region with XOR swizzle
//    (off ^= ((off>>9)&7)<<5 on both write and read) -> no bank conflicts.
//  - 2 barriers per block total (was 8). s_setprio(1) around MFMA clusters.

typedef __bf16 bf16;
typedef __attribute__((ext_vector_type(8)))  __bf16 bf16x8;
typedef __attribute__((ext_vector_type(4)))  float  f32x4;
typedef __attribute__((ext_vector_type(16))) float  f32x16;

#define N_EDGES 640000
#define BM      64
#define NTHR    256

// ---------------- weight prep: fp32 row-major -> bf16 fragment-linear ----------
// W1 frags: [nt(4)][ks(20)][lane(64)][j(8)]  element = W1[k*128+n],
//   n = nt*32 + (lane&31), k = ks*16 + (lane>>5)*8 + j     (40960 elems)
// W2 frags: [nt(4)][ks(8)][lane(64)][j(8)]   element = W2[k*128+n]  (16384 elems)
__global__ void prep_weights(const float* __restrict__ W1, const float* __restrict__ W2,
                             bf16* __restrict__ w1f, bf16* __restrict__ w2f) {
    int i = blockIdx.x * 256 + threadIdx.x;
    if (i < 40960) {
        int j = i & 7, l = (i >> 3) & 63, q = i >> 9;   // q in [0,80)
        int ks = q % 20, nt = q / 20;
        int n = nt * 32 + (l & 31);
        int k = ks * 16 + ((l >> 5) << 3) + j;
        w1f[i] = (bf16)W1[k * 128 + n];
    } else if (i < 40960 + 16384) {
        int i2 = i - 40960;
        int j = i2 & 7, l = (i2 >> 3) & 63, q = i2 >> 9; // q in [0,32)
        int ks = q & 7, nt = q >> 3;
        int n = nt * 32 + (l & 31);
        int k = ks * 16 + ((l >> 5) << 3) + j;
        w2f[i2] = (bf16)W2[k * 128 + n];
    }
}

__global__ __launch_bounds__(NTHR, 2) void edge_mlp(
    const float* __restrict__ x, const int* __restrict__ eidx,
    const float* __restrict__ eattr, const bf16* __restrict__ w1f,
    const float* __restrict__ b1, const bf16* __restrict__ w2f,
    const float* __restrict__ b2, float* __restrict__ out)
{
    extern __shared__ char smem[];
    bf16* sA = (bf16*)smem;          // 40 blocks(mt*20+ks) x 64 granules x 16 B = 40960 B
    char* sH = smem + 40960;         // 16 blocks(mt*8+ks2) x 1024 B = 16384 B (swizzled)

    const int tid   = threadIdx.x;
    const int wave  = tid >> 6;      // wave w owns output cols [32w, 32w+32)
    const int lane  = tid & 63;
    const int ebase = blockIdx.x * BM;

    // ---- stage A (64 x 320 fp32 -> bf16) into fragment-linear LDS.
    // slot = granule index; thread writes granule (slot) fully: lane-linear ->
    // conflict-free ds_write_b128. blk is wave-uniform (blk = i*4 + wave).
#pragma unroll
    for (int i = 0; i < 10; ++i) {
        const int slot = i * NTHR + tid;
        const int blk  = slot >> 6;                 // 0..39, wave-uniform
        const int sub  = slot & 63;
        const int mt   = blk / 20;
        const int ks   = blk % 20;
        const int m    = mt * 32 + (sub & 31);
        const int k    = ks * 16 + ((sub >> 5) << 3);
        f32x4 v0, v1;
        if (ks < 8) {                                // x[src[m]], cols 0..127
            const f32x4* p = (const f32x4*)(x + (size_t)eidx[ebase + m] * 128 + k);
            v0 = p[0]; v1 = p[1];
        } else if (ks < 16) {                        // x[tgt[m]], cols 128..255
            const f32x4* p = (const f32x4*)(x + (size_t)eidx[N_EDGES + ebase + m] * 128 + (k - 128));
            v0 = p[0]; v1 = p[1];
        } else {                                     // edge_attr, cols 256..319 (streaming)
            const f32x4* p = (const f32x4*)(eattr + (size_t)(ebase + m) * 64 + (k - 256));
            v0 = __builtin_nontemporal_load(p);
            v1 = __builtin_nontemporal_load(p + 1);
        }
        bf16x8 bv;
        bv[0] = (bf16)v0.x; bv[1] = (bf16)v0.y; bv[2] = (bf16)v0.z; bv[3] = (bf16)v0.w;
        bv[4] = (bf16)v1.x; bv[5] = (bf16)v1.y; bv[6] = (bf16)v1.z; bv[7] = (bf16)v1.w;
        *(bf16x8*)&sA[slot * 8] = bv;
    }

    // ---- W1 fragments for this wave's nt slice -> 80 VGPR (L2-hot, coalesced)
    bf16x8 w1r[20];
    {
        const bf16x8* wp = (const bf16x8*)w1f + (wave * 20 * 64 + lane);
#pragma unroll
        for (int ks = 0; ks < 20; ++ks) w1r[ks] = wp[ks * 64];
    }

    f32x16 acc0, acc1;
#pragma unroll
    for (int i = 0; i < 16; ++i) { acc0[i] = 0.f; acc1[i] = 0.f; }

    __syncthreads();                                 // A staged

    // ---- GEMM1: acc[mt] += A[mt] @ W1[:,nt]   (K = 320)
    __builtin_amdgcn_s_setprio(1);
#pragma unroll
    for (int ks = 0; ks < 20; ++ks) {
        bf16x8 a0 = *(const bf16x8*)&sA[((0 * 20 + ks) * 64 + lane) * 8];
        bf16x8 a1 = *(const bf16x8*)&sA[((1 * 20 + ks) * 64 + lane) * 8];
        acc0 = __builtin_amdgcn_mfma_f32_32x32x16_bf16(a0, w1r[ks], acc0, 0, 0, 0);
        acc1 = __builtin_amdgcn_mfma_f32_32x32x16_bf16(a1, w1r[ks], acc1, 0, 0, 0);
    }
    __builtin_amdgcn_s_setprio(0);

    // ---- W2 fragments -> 32 VGPR (W1 regs dead now)
    bf16x8 w2r[8];
    {
        const bf16x8* wp = (const bf16x8*)w2f + (wave * 8 * 64 + lane);
#pragma unroll
        for (int ks = 0; ks < 8; ++ks) w2r[ks] = wp[ks * 64];
    }

    // ---- h = relu(acc + b1) -> sH in A-frag layout, XOR-swizzled.
    // C layout: col = lane&31, row = (r&3) + 8*(r>>2) + 4*(lane>>5).
    // h[m][kn] granule byte off = (mt*8 + kn>>4)*1024 + ((m&31)+((kn>>3)&1)*32)*16
    //   + (kn&7)*2 ; swizzle key = (off>>9)&7 = (kn>>3)&7 (constant per lane).
    {
        const int   ln   = lane & 31;
        const int   kn   = wave * 32 + ln;
        const int   rowq = (lane >> 5) << 2;
        const float b1v  = b1[kn];
        const int   colb = ((kn >> 4) * 64 + ((kn >> 3) & 1) * 32) * 16 + (kn & 7) * 2;
        const int   kx   = ((kn >> 3) & 7) << 5;
#pragma unroll
        for (int r = 0; r < 16; ++r) {
            const int ml  = (r & 3) + ((r >> 2) << 3) + rowq;
            const int off = colb + ml * 16;
            *(bf16*)(sH + ((off       ) ^ kx)) = (bf16)fmaxf(acc0[r] + b1v, 0.f);
            *(bf16*)(sH + ((off + 8192) ^ kx)) = (bf16)fmaxf(acc1[r] + b1v, 0.f);
        }
    }
    __syncthreads();                                 // h visible to all waves

    // ---- GEMM2: out = h @ W2[:,nt] + b2   (K = 128)
#pragma unroll
    for (int i = 0; i < 16; ++i) { acc0[i] = 0.f; acc1[i] = 0.f; }
    __builtin_amdgcn_s_setprio(1);
#pragma unroll
    for (int ks = 0; ks < 8; ++ks) {
        int o0 = ((0 * 8 + ks) * 64 + lane) * 16;
        int o1 = ((1 * 8 + ks) * 64 + lane) * 16;
        o0 ^= ((o0 >> 9) & 7) << 5;                  // same involution as writes
        o1 ^= ((o1 >> 9) & 7) << 5;
        bf16x8 a0 = *(const bf16x8*)(sH + o0);
        bf16x8 a1 = *(const bf16x8*)(sH + o1);
        acc0 = __builtin_amdgcn_mfma_f32_32x32x16_bf16(a0, w2r[ks], acc0, 0, 0, 0);
        acc1 = __builtin_amdgcn_mfma_f32_32x32x16_bf16(a1, w2r[ks], acc1, 0, 0, 0);
    }
    __builtin_amdgcn_s_setprio(0);

    // ---- epilogue: out rows = ebase + mt*32 + ml, col n (coalesced, streaming)
    {
        const int   ln   = lane & 31;
        const int   n    = wave * 32 + ln;
        const int   rowq = (lane >> 5) << 2;
        const float b2v  = b2[n];
#pragma unroll
        for (int r = 0; r < 16; ++r) {
            const int ml = (r & 3) + ((r >> 2) << 3) + rowq;
            __builtin_nontemporal_store(acc0[r] + b2v, &out[(size_t)(ebase      + ml) * 128 + n]);
            __builtin_nontemporal_store(acc1[r] + b2v, &out[(size_t)(ebase + 32 + ml) * 128 + n]);
        }
    }
}

extern "C" void kernel_launch(void* const* d_in, const int* in_sizes, int n_in,
                              void* d_out, int out_size, void* d_ws, size_t ws_size,
                              hipStream_t stream) {
    const float* x   = (const float*)d_in[0];
    const int*   ei  = (const int*)d_in[1];
    const float* ea  = (const float*)d_in[2];
    const float* W1  = (const float*)d_in[3];
    const float* b1  = (const float*)d_in[4];
    const float* W2  = (const float*)d_in[5];
    const float* b2  = (const float*)d_in[6];
    float*       out = (float*)d_out;

    bf16* w1f = (bf16*)d_ws;                          // 40960 bf16 = 81920 B
    bf16* w2f = (bf16*)((char*)d_ws + 81920);         // 16384 bf16 = 32768 B

    prep_weights<<<224, 256, 0, stream>>>(W1, W2, w1f, w2f);

    const size_t shmem = 40960 + 16384;               // 56 KB -> 2 blocks/CU
    edge_mlp<<<N_EDGES / BM, NTHR, shmem, stream>>>(x, ei, ea, w1f, b1, w2f, b2, out);
}

// Round 4
// 579.500 us; speedup vs baseline: 1.0710x; 1.0710x over previous
//
#include <hip/hip_runtime.h>

// Edge MLP: out = relu(concat(x[src], x[tgt], edge_attr) @ W1 + b1) @ W2 + b2
// E=640000, NODE=128, EA=64, IN=320, OUT=128. fp32 in/out, bf16 MFMA compute.
//
// v3: persistent blocks + in-block software pipeline.
//  - grid = 512 blocks (2/CU), each block processes ~19.5 tiles of BM=64 edges.
//  - W1/W2 fragments loaded into VGPR ONCE per block (80+32 regs); all edge
//    indices for the block staged into LDS once (10 KB).
//  - Per tile, T14-style 2-chunk reg-staged prefetch of tile t+1:
//      chunk0 issue -> GEMM1(t) -> barrier -> chunk0 ds_write + chunk1 issue
//      -> h(t) -> barrier -> GEMM2(t) -> stores(t) -> chunk1 ds_write -> barrier
//    Loads stay outstanding under every compute phase (fixes v2's regression:
//    2 blocks/CU were resident but strictly serial per-phase; memory idled).
//  - Staging granules + swizzled h round-trip identical to v2 (measured 0
//    LDS bank conflicts).

typedef __bf16 bf16;
typedef __attribute__((ext_vector_type(8)))  __bf16 bf16x8;
typedef __attribute__((ext_vector_type(4)))  float  f32x4;
typedef __attribute__((ext_vector_type(16))) float  f32x16;

#define N_EDGES 640000
#define BM      64
#define NTHR    256
#define NBLK    512
#define TILES   (N_EDGES / BM)     // 10000
#define TPB     (TILES / NBLK)     // 19
#define TREM    (TILES % NBLK)     // 272

// ---------------- weight prep: fp32 row-major -> bf16 fragment-linear ----------
// W1 frags: [nt(4)][ks(20)][lane(64)][j(8)]  element = W1[k*128+n],
//   n = nt*32 + (lane&31), k = ks*16 + (lane>>5)*8 + j     (40960 elems)
// W2 frags: [nt(4)][ks(8)][lane(64)][j(8)]   element = W2[k*128+n]  (16384 elems)
__global__ void prep_weights(const float* __restrict__ W1, const float* __restrict__ W2,
                             bf16* __restrict__ w1f, bf16* __restrict__ w2f) {
    int i = blockIdx.x * 256 + threadIdx.x;
    if (i < 40960) {
        int j = i & 7, l = (i >> 3) & 63, q = i >> 9;   // q in [0,80)
        int ks = q % 20, nt = q / 20;
        int n = nt * 32 + (l & 31);
        int k = ks * 16 + ((l >> 5) << 3) + j;
        w1f[i] = (bf16)W1[k * 128 + n];
    } else if (i < 40960 + 16384) {
        int i2 = i - 40960;
        int j = i2 & 7, l = (i2 >> 3) & 63, q = i2 >> 9; // q in [0,32)
        int ks = q & 7, nt = q >> 3;
        int n = nt * 32 + (l & 31);
        int k = ks * 16 + ((l >> 5) << 3) + j;
        w2f[i2] = (bf16)W2[k * 128 + n];
    }
}

// Stage-granule geometry: slot = g*256+tid, blk = slot>>6 = g*4+wave (uniform),
// mt = blk>=20, ks = blk - mt*20, row m = mt*32+(lane&31), k-half = (lane>>5)*8.
// LDS dest = slot*16 bytes: lane-linear -> conflict-free ds_write_b128.
#define STG_ISSUE(g, tloc, d0, d1) {                                                  \
    const int blk_ = (g) * 4 + wave;                                                  \
    const int mq_  = (blk_ >= 20) ? 1 : 0;                                            \
    const int ks_  = blk_ - mq_ * 20;                                                 \
    const int m_   = mq_ * 32 + (lane & 31);                                          \
    const int kh_  = (lane >> 5) << 3;                                                \
    if (ks_ < 8) {                                                                    \
        const f32x4* p_ = (const f32x4*)(x + (size_t)sIdx[(tloc)*128 + m_] * 128      \
                                           + ks_ * 16 + kh_);                         \
        d0 = p_[0]; d1 = p_[1];                                                       \
    } else if (ks_ < 16) {                                                            \
        const f32x4* p_ = (const f32x4*)(x + (size_t)sIdx[(tloc)*128 + 64 + m_] * 128 \
                                           + (ks_ - 8) * 16 + kh_);                   \
        d0 = p_[0]; d1 = p_[1];                                                       \
    } else {                                                                          \
        const f32x4* p_ = (const f32x4*)(eattr + ((size_t)(tbase + (tloc)) * 64 + m_) * 64 \
                                           + (ks_ - 16) * 16 + kh_);                  \
        d0 = __builtin_nontemporal_load(p_);                                          \
        d1 = __builtin_nontemporal_load(p_ + 1);                                      \
    } }

#define STG_WRITE(g, d0, d1) {                                                        \
    bf16x8 bv_;                                                                       \
    bv_[0] = (bf16)d0.x; bv_[1] = (bf16)d0.y; bv_[2] = (bf16)d0.z; bv_[3] = (bf16)d0.w; \
    bv_[4] = (bf16)d1.x; bv_[5] = (bf16)d1.y; bv_[6] = (bf16)d1.z; bv_[7] = (bf16)d1.w; \
    *(bf16x8*)&sA[((g) * NTHR + tid) * 8] = bv_; }

__global__ __launch_bounds__(NTHR, 2) void edge_mlp(
    const float* __restrict__ x, const int* __restrict__ eidx,
    const float* __restrict__ eattr, const bf16* __restrict__ w1f,
    const float* __restrict__ b1, const bf16* __restrict__ w2f,
    const float* __restrict__ b2, float* __restrict__ out)
{
    extern __shared__ char smem[];
    bf16* sA   = (bf16*)smem;                   // 40960 B: 40 blk x 64 granules x 16 B
    char* sH   = smem + 40960;                  // 16384 B (XOR-swizzled h)
    int*  sIdx = (int*)(smem + 40960 + 16384);  // 10240 B: [tile(<=20)][src 64 | tgt 64]

    const int tid   = threadIdx.x;
    const int wave  = tid >> 6;     // wave w owns output cols [32w, 32w+32)
    const int lane  = tid & 63;
    const int b     = blockIdx.x;
    const int count = TPB + (b < TREM ? 1 : 0);
    const int tbase = b * TPB + (b < TREM ? b : TREM);

    // ---- all edge indices for this block -> sIdx (coalesced, once)
    const int nE = count * BM;
    for (int i = tid; i < nE; i += NTHR) {
        const int tt = i >> 6, m = i & 63;
        sIdx[tt * 128 + m]      = eidx[tbase * BM + i];
        sIdx[tt * 128 + 64 + m] = eidx[N_EDGES + tbase * BM + i];
    }

    // ---- W1/W2 fragments for this wave's nt slice -> VGPR (once per block)
    bf16x8 w1r[20];
    {
        const bf16x8* wp = (const bf16x8*)w1f + (wave * 20 * 64 + lane);
#pragma unroll
        for (int ks = 0; ks < 20; ++ks) w1r[ks] = wp[ks * 64];
    }
    bf16x8 w2r[8];
    {
        const bf16x8* wp = (const bf16x8*)w2f + (wave * 8 * 64 + lane);
#pragma unroll
        for (int ks = 0; ks < 8; ++ks) w2r[ks] = wp[ks * 64];
    }
    const int   kn   = wave * 32 + (lane & 31);
    const int   rowq = (lane >> 5) << 2;
    const float b1v  = b1[kn];
    const float b2v  = b2[kn];
    const int   colb = ((kn >> 4) * 64 + ((kn >> 3) & 1) * 32) * 16 + (kn & 7) * 2;
    const int   kx   = ((kn >> 3) & 7) << 5;

    __syncthreads();                             // sIdx visible

    // ---- prologue: stage tile 0 into sA
    {
        f32x4 p0[5], p1[5];
#pragma unroll
        for (int g = 0; g < 5; ++g) STG_ISSUE(g, 0, p0[g], p1[g]);
#pragma unroll
        for (int g = 0; g < 5; ++g) STG_WRITE(g, p0[g], p1[g]);
#pragma unroll
        for (int g = 5; g < 10; ++g) STG_ISSUE(g, 0, p0[g - 5], p1[g - 5]);
#pragma unroll
        for (int g = 5; g < 10; ++g) STG_WRITE(g, p0[g - 5], p1[g - 5]);
    }
    __syncthreads();                             // sA(t=0) visible

    for (int t = 0; t < count; ++t) {
        const bool pf = (t + 1 < count);
        f32x4 p0[5], p1[5];

        // ---- prefetch chunk0 of tile t+1 (in flight under GEMM1)
        if (pf) {
#pragma unroll
            for (int g = 0; g < 5; ++g) STG_ISSUE(g, t + 1, p0[g], p1[g]);
        }

        // ---- GEMM1: acc[mt] += A[mt] @ W1[:,nt]   (K = 320)
        f32x16 acc0, acc1;
#pragma unroll
        for (int i = 0; i < 16; ++i) { acc0[i] = 0.f; acc1[i] = 0.f; }
        __builtin_amdgcn_s_setprio(1);
#pragma unroll
        for (int ks = 0; ks < 20; ++ks) {
            bf16x8 a0 = *(const bf16x8*)&sA[((     ks) * 64 + lane) * 8];
            bf16x8 a1 = *(const bf16x8*)&sA[((20 + ks) * 64 + lane) * 8];
            acc0 = __builtin_amdgcn_mfma_f32_32x32x16_bf16(a0, w1r[ks], acc0, 0, 0, 0);
            acc1 = __builtin_amdgcn_mfma_f32_32x32x16_bf16(a1, w1r[ks], acc1, 0, 0, 0);
        }
        __builtin_amdgcn_s_setprio(0);
        __syncthreads();                         // all sA reads done

        // ---- commit chunk0, prefetch chunk1 (in flight under h + GEMM2 + stores)
        if (pf) {
#pragma unroll
            for (int g = 0; g < 5; ++g) STG_WRITE(g, p0[g], p1[g]);
#pragma unroll
            for (int g = 5; g < 10; ++g) STG_ISSUE(g, t + 1, p0[g - 5], p1[g - 5]);
        }

        // ---- h = relu(acc + b1) -> sH (XOR-swizzled; conflict-free)
#pragma unroll
        for (int r = 0; r < 16; ++r) {
            const int ml  = (r & 3) + ((r >> 2) << 3) + rowq;
            const int off = colb + ml * 16;
            *(bf16*)(sH + ((off       ) ^ kx)) = (bf16)fmaxf(acc0[r] + b1v, 0.f);
            *(bf16*)(sH + ((off + 8192) ^ kx)) = (bf16)fmaxf(acc1[r] + b1v, 0.f);
        }
        __syncthreads();                         // h visible

        // ---- GEMM2: out = h @ W2[:,nt] + b2   (K = 128)
#pragma unroll
        for (int i = 0; i < 16; ++i) { acc0[i] = 0.f; acc1[i] = 0.f; }
        __builtin_amdgcn_s_setprio(1);
#pragma unroll
        for (int ks = 0; ks < 8; ++ks) {
            int o0 = ((     ks) * 64 + lane) * 16;
            int o1 = ((8 +  ks) * 64 + lane) * 16;
            o0 ^= ((o0 >> 9) & 7) << 5;          // same involution as writes
            o1 ^= ((o1 >> 9) & 7) << 5;
            bf16x8 a0 = *(const bf16x8*)(sH + o0);
            bf16x8 a1 = *(const bf16x8*)(sH + o1);
            acc0 = __builtin_amdgcn_mfma_f32_32x32x16_bf16(a0, w2r[ks], acc0, 0, 0, 0);
            acc1 = __builtin_amdgcn_mfma_f32_32x32x16_bf16(a1, w2r[ks], acc1, 0, 0, 0);
        }
        __builtin_amdgcn_s_setprio(0);

        // ---- epilogue: coalesced streaming store
        {
            const size_t ebase = (size_t)(tbase + t) * BM;
#pragma unroll
            for (int r = 0; r < 16; ++r) {
                const int ml = (r & 3) + ((r >> 2) << 3) + rowq;
                __builtin_nontemporal_store(acc0[r] + b2v, &out[(ebase      + ml) * 128 + kn]);
                __builtin_nontemporal_store(acc1[r] + b2v, &out[(ebase + 32 + ml) * 128 + kn]);
            }
        }

        // ---- commit chunk1 of tile t+1
        if (pf) {
#pragma unroll
            for (int g = 5; g < 10; ++g) STG_WRITE(g, p0[g - 5], p1[g - 5]);
        }
        __syncthreads();                         // sA(t+1) visible for next GEMM1
    }
}

extern "C" void kernel_launch(void* const* d_in, const int* in_sizes, int n_in,
                              void* d_out, int out_size, void* d_ws, size_t ws_size,
                              hipStream_t stream) {
    const float* x   = (const float*)d_in[0];
    const int*   ei  = (const int*)d_in[1];
    const float* ea  = (const float*)d_in[2];
    const float* W1  = (const float*)d_in[3];
    const float* b1  = (const float*)d_in[4];
    const float* W2  = (const float*)d_in[5];
    const float* b2  = (const float*)d_in[6];
    float*       out = (float*)d_out;

    bf16* w1f = (bf16*)d_ws;                          // 40960 bf16 = 81920 B
    bf16* w2f = (bf16*)((char*)d_ws + 81920);         // 16384 bf16 = 32768 B

    prep_weights<<<224, 256, 0, stream>>>(W1, W2, w1f, w2f);

    const size_t shmem = 40960 + 16384 + 10240;       // 67584 B -> 2 blocks/CU
    edge_mlp<<<NBLK, NTHR, shmem, stream>>>(x, ei, ea, w1f, b1, w2f, b2, out);
}